// Round 8
// baseline (24561.540 us; speedup 1.0000x reference)
//
#include <hip/hip_runtime.h>
#include <math.h>

#define BATCH 128
#define TSTEPS 1024
#define INSZ 256
#define HSZ 256
#define MEMN 128

#define NWG_A 128
#define NWG_B 64
#define NWG_C 32
#define NWG 224
#define NTHR 256

#define GATE_C 0.40131233988754794f
#define OMG_C  (1.0f - GATE_C)
#define GAMMA_C 0.3f

// ---- per-step state, unique slot per t; coherence via kernel launch boundaries ----
__device__ float g_hT [(size_t)TSTEPS * HSZ * BATCH];        // hT(t)[j][b]
__device__ float g_M  [(size_t)TSTEPS * MEMN * HSZ];         // M(t)[m][j], slots 1..1023
__device__ float g_Mn [(size_t)TSTEPS * MEMN];               // Mn(t)[m]
__device__ float g_ww [(size_t)(TSTEPS + 1) * BATCH * MEMN]; // ww(t)[b][m], slots 1..1024
__device__ float g_wu [(size_t)(TSTEPS + 1) * BATCH * MEMN]; // wu(t)[b][m], slots 1..1024
__device__ float g_cst[BATCH * HSZ];                         // c, in-place (same-thread RW)

__device__ __forceinline__ float sigf(float x) { return 1.0f / (1.0f + expf(-x)); }

__global__ void __launch_bounds__(NTHR, 1)
step_kernel(const int t,
            const float* __restrict__ X, const float* __restrict__ Wih,
            const float* __restrict__ Whh, const float* __restrict__ bih,
            const float* __restrict__ bhh, float* __restrict__ out) {
    __shared__ float4 s_x4[64 * 128];   // A: xh tile (128 KB); B aliases as s_M
    __shared__ float s_aux[4096];       // A: partials; B carve
    __shared__ float s_red8[8];
    __shared__ float s_red16[16];
    __shared__ unsigned long long s_redu8[8];

    const int w = blockIdx.x, tid = threadIdx.x;
    const int lane = tid & 63, wv = tid >> 6;

    auto grpsum = [&](float v) -> float {
#pragma unroll
        for (int o = 32; o; o >>= 1) v += __shfl_xor(v, o, 64);
        if (lane == 0) s_red8[wv] = v;
        __syncthreads();
        float r = s_red8[(tid >> 7) * 2] + s_red8[(tid >> 7) * 2 + 1];
        __syncthreads();
        return r;
    };
    auto grpmax = [&](float v) -> float {
#pragma unroll
        for (int o = 32; o; o >>= 1) v = fmaxf(v, __shfl_xor(v, o, 64));
        if (lane == 0) s_red8[wv] = v;
        __syncthreads();
        float r = fmaxf(s_red8[(tid >> 7) * 2], s_red8[(tid >> 7) * 2 + 1]);
        __syncthreads();
        return r;
    };
    auto grpminu = [&](unsigned long long v) -> unsigned long long {
#pragma unroll
        for (int o = 32; o; o >>= 1) {
            unsigned long long o2 = __shfl_xor(v, o, 64);
            v = (o2 < v) ? o2 : v;
        }
        if (lane == 0) s_redu8[wv] = v;
        __syncthreads();
        unsigned long long a = s_redu8[(tid >> 7) * 2], b2 = s_redu8[(tid >> 7) * 2 + 1];
        unsigned long long r = (a < b2) ? a : b2;
        __syncthreads();
        return r;
    };
    auto red256sum4 = [&](float v0, float v1, float v2, float v3, float (&r)[4]) {
#pragma unroll
        for (int o = 32; o; o >>= 1) {
            v0 += __shfl_xor(v0, o, 64);
            v1 += __shfl_xor(v1, o, 64);
            v2 += __shfl_xor(v2, o, 64);
            v3 += __shfl_xor(v3, o, 64);
        }
        if (lane == 0) {
            s_red16[wv * 4 + 0] = v0; s_red16[wv * 4 + 1] = v1;
            s_red16[wv * 4 + 2] = v2; s_red16[wv * 4 + 3] = v3;
        }
        __syncthreads();
#pragma unroll
        for (int k = 0; k < 4; ++k)
            r[k] = (s_red16[0 * 4 + k] + s_red16[1 * 4 + k]) +
                   (s_red16[2 * 4 + k] + s_red16[3 * 4 + k]);
        __syncthreads();
    };

    if (w < NWG_A) {
        // ================= A: h(t) from h(t-1) =================
        if (t >= TSTEPS) return;
        const int bb = w >> 6, jb = w & 63;
        const int bglob = bb * 64 + lane;
        const int jglob = jb * 4 + wv;
        const int cidx = bglob * HSZ + jglob;
        float biasA[4];
#pragma unroll
        for (int g = 0; g < 4; ++g) {
            const int row = g * HSZ + jb * 4 + wv;
            biasA[g] = bih[row] + bhh[row];
        }
        const float cold = (t == 0) ? 0.f : g_cst[cidx];  // early issue

        // stage X(t) -> LDS X-region
        {
            const int kq = tid & 63, bofs = tid >> 6;
#pragma unroll 4
            for (int rep = 0; rep < 16; ++rep) {
                const int b = rep * 4 + bofs;
                const float4 v = *(const float4*)(X + ((size_t)(bb * 64 + b) * TSTEPS + t) * INSZ + kq * 4);
                s_x4[b * 128 + (kq ^ (b & 7))] = v;
            }
        }
        // issue h(t-1) gather (lands under Wih compute)
        float4 hv[16];
        if (t > 0) {
#pragma unroll
            for (int rep = 0; rep < 16; ++rep) {
                const int j0 = (wv * 16 + rep) * 4;
                const size_t base = ((size_t)(t - 1) * HSZ + j0) * BATCH + bglob;
                float4 v;
                v.x = g_hT[base];
                v.y = g_hT[base + BATCH];
                v.z = g_hT[base + 2 * BATCH];
                v.w = g_hT[base + 3 * BATCH];
                hv[rep] = v;
            }
        } else {
            const float4 z4 = make_float4(0.f, 0.f, 0.f, 0.f);
#pragma unroll
            for (int rep = 0; rep < 16; ++rep) hv[rep] = z4;
        }
        __syncthreads();  // X staged

        float acc[16];
#pragma unroll
        for (int i = 0; i < 16; ++i) acc[i] = 0.f;
        auto computeRegion = [&](float (&a16)[16], const float* __restrict__ Wb, const int kofs) {
            const int kbase = kofs + wv * 64;
#pragma unroll 4
            for (int k4 = 0; k4 < 16; ++k4) {
                const int kg = kbase + k4 * 4;
                const float4 xv = s_x4[lane * 128 + ((kg >> 2) ^ (lane & 7))];
                const int kl = kg - kofs;
#pragma unroll
                for (int rr = 0; rr < 16; ++rr) {
                    const int grow = (rr >> 2) * HSZ + jb * 4 + (rr & 3);
                    const float4 wv4 = *(const float4*)(Wb + (size_t)grow * 256 + kl);
                    a16[rr] += wv4.x * xv.x + wv4.y * xv.y + wv4.z * xv.z + wv4.w * xv.w;
                }
            }
        };
        computeRegion(acc, Wih, 0);
#pragma unroll
        for (int rep = 0; rep < 16; ++rep)
            s_x4[lane * 128 + ((64 + wv * 16 + rep) ^ (lane & 7))] = hv[rep];
        __syncthreads();
        computeRegion(acc, Whh, 256);
#pragma unroll
        for (int rr = 0; rr < 16; ++rr) s_aux[(wv * 16 + rr) * 64 + lane] = acc[rr];
        __syncthreads();
        float z[4];
#pragma unroll
        for (int g = 0; g < 4; ++g) {
            const int rr = g * 4 + wv;
            z[g] = ((s_aux[rr * 64 + lane] + s_aux[(16 + rr) * 64 + lane]) +
                    (s_aux[(32 + rr) * 64 + lane] + s_aux[(48 + rr) * 64 + lane])) + biasA[g];
        }
        const float cn = sigf(z[1]) * cold + sigf(z[0]) * tanhf(z[2]);
        const float hn = sigf(z[3]) * tanhf(cn);
        g_cst[cidx] = cn;
        g_hT[((size_t)t * HSZ + jglob) * BATCH + bglob] = hn;
    } else if (w < NWG_A + NWG_B) {
        // ================= B': step s = t-1 (read head, out, w_u/w_w) =================
        if (t < 1) return;
        const int s = t - 1;
        const int bwg = w - NWG_A;
        const int grp = tid >> 7, lm = tid & 127;
        const int bB = bwg * 2 + grp;
        float* s_M = (float*)s_x4;
        float* s_h2 = s_aux;
        float* s_wr2 = s_aux + 512;

        if (s > 0) {  // stage M(s) -> LDS (all inputs valid at kernel start)
            float4 mt[32];
            const float4* msrc = (const float4*)&g_M[(size_t)s * MEMN * HSZ];
#pragma unroll
            for (int i = 0; i < 32; ++i) mt[i] = msrc[i * 256 + tid];
            float4* md = (float4*)s_M;
#pragma unroll
            for (int i = 0; i < 32; ++i) md[i * 256 + tid] = mt[i];
        }
        s_h2[grp * 256 + lm] = g_hT[((size_t)s * HSZ + lm) * BATCH + bB];
        s_h2[grp * 256 + lm + 128] = g_hT[((size_t)s * HSZ + lm + 128) * BATCH + bB];
        const float wu_prev = (s > 0) ? g_wu[((size_t)s * BATCH + bB) * MEMN + lm] : 0.f;
        const float ww_prev = (s > 0) ? g_ww[((size_t)s * BATCH + bB) * MEMN + lm]
                                      : ((lm == 0) ? OMG_C : 0.f);
        __syncthreads();
        const float hv0 = s_h2[grp * 256 + lm], hv1 = s_h2[grp * 256 + lm + 128];
        const float hnorm = sqrtf(grpsum(hv0 * hv0 + hv1 * hv1));
        float sc = 0.f;
        if (s > 0) {
            const float4* mrow = (const float4*)&s_M[(size_t)lm * HSZ];
            const float4* h4 = (const float4*)&s_h2[grp * 256];
            const int sw = lm & 7;
            float a = 0.f;
#pragma unroll 8
            for (int c = 0; c < 64; ++c) {
                const int ci = c ^ sw;
                const float4 m4 = mrow[ci], x4 = h4[ci];
                a += m4.x * x4.x + m4.y * x4.y + m4.z * x4.z + m4.w * x4.w;
            }
            const float mn = g_Mn[(size_t)s * MEMN + lm];
            sc = a / (hnorm * mn + 1e-8f);
        }
        const float mx = grpmax(sc);
        const float ev = expf(sc - mx);
        const float es = grpsum(ev);
        const float wr = ev / es;
        s_wr2[grp * 128 + lm] = wr;
        __syncthreads();
        float rd0 = 0.f, rd1 = 0.f;
        if (s > 0) {
#pragma unroll 8
            for (int m = 0; m < 128; ++m) {
                const float mv = s_M[m * HSZ + tid];
                rd0 += s_wr2[m] * mv;
                rd1 += s_wr2[128 + m] * mv;
            }
        }
        const int b0 = bwg * 2, b1 = b0 + 1;
        float* o0 = out + ((size_t)b0 * TSTEPS + s) * 512;
        float* o1 = out + ((size_t)b1 * TSTEPS + s) * 512;
        o0[tid] = s_h2[tid];
        o1[tid] = s_h2[256 + tid];
        o0[256 + tid] = rd0;
        o1[256 + tid] = rd1;
        // w_u(s+1) = l2norm(gamma*w_u(s) + w_r(s) + w_w(s)); w_w(s+1) from argmin
        const float un = GAMMA_C * wu_prev + wr + ww_prev;
        const float un2 = grpsum(un * un);
        const float us = 1.0f / fmaxf(sqrtf(un2), 1e-12f);
        const float wun = un * us;
        g_wu[((size_t)(s + 1) * BATCH + bB) * MEMN + lm] = wun;
        unsigned long long key =
            (((unsigned long long)__float_as_uint(wun)) << 32) | (unsigned)lm;
        const unsigned long long mk = grpminu(key);
        const int amin = (int)(mk & 0xffffffffu);
        const float wwn = GATE_C * wr + ((lm == amin) ? OMG_C : 0.f);
        g_ww[((size_t)(s + 1) * BATCH + bB) * MEMN + lm] = wwn;
    } else if (w < NWG) {
        // ================= C': M(s+1) = l2norm(M(s) + ww(s)^T h(s)), s = t-1 =================
        if (t < 1 || t - 1 >= TSTEPS - 1) return;
        const int s = t - 1;
        const int cwg = w - NWG_A - NWG_B;
        const int m0 = cwg * 4;
        float* s_wwc = s_aux;  // [4][128]
        {
            const int e0 = tid, e1 = tid + 256;
            float v0, v1;
            if (s > 0) {
                v0 = g_ww[((size_t)s * BATCH + (e0 >> 2)) * MEMN + m0 + (e0 & 3)];
                v1 = g_ww[((size_t)s * BATCH + (e1 >> 2)) * MEMN + m0 + (e1 & 3)];
            } else {
                v0 = (m0 + (e0 & 3) == 0) ? OMG_C : 0.f;
                v1 = (m0 + (e1 & 3) == 0) ? OMG_C : 0.f;
            }
            s_wwc[(e0 & 3) * 128 + (e0 >> 2)] = v0;
            s_wwc[(e1 & 3) * 128 + (e1 >> 2)] = v1;
        }
        float macc[4];
#pragma unroll
        for (int mi = 0; mi < 4; ++mi)
            macc[mi] = (s > 0) ? g_M[((size_t)s * MEMN + m0 + mi) * HSZ + tid] : 0.f;
        float4 hb[32];
        const float4* ht4 = (const float4*)&g_hT[((size_t)s * HSZ + tid) * BATCH];
#pragma unroll
        for (int q = 0; q < 32; ++q) hb[q] = ht4[q];
        __syncthreads();
#pragma unroll
        for (int b4 = 0; b4 < 32; ++b4) {
            const float4 hv4 = hb[b4];
#pragma unroll
            for (int mi = 0; mi < 4; ++mi) {
                const float* wc = &s_wwc[mi * 128 + b4 * 4];
                macc[mi] += wc[0] * hv4.x + wc[1] * hv4.y + wc[2] * hv4.z + wc[3] * hv4.w;
            }
        }
        float nr[4];
        red256sum4(macc[0] * macc[0], macc[1] * macc[1],
                   macc[2] * macc[2], macc[3] * macc[3], nr);
#pragma unroll
        for (int mi = 0; mi < 4; ++mi) {
            const float nrm = sqrtf(nr[mi]);
            const float scale = 1.0f / fmaxf(nrm, 1e-12f);
            const float vo = macc[mi] * scale;
            g_M[((size_t)(s + 1) * MEMN + m0 + mi) * HSZ + tid] = vo;
            if (tid == 0) g_Mn[(size_t)(s + 1) * MEMN + m0 + mi] = nrm * scale;
        }
    }
}

extern "C" void kernel_launch(void* const* d_in, const int* in_sizes, int n_in,
                              void* d_out, int out_size, void* d_ws, size_t ws_size,
                              hipStream_t stream) {
    const float* X   = (const float*)d_in[0];
    const float* Wih = (const float*)d_in[1];
    const float* Whh = (const float*)d_in[2];
    const float* bih = (const float*)d_in[3];
    const float* bhh = (const float*)d_in[4];
    float* out = (float*)d_out;
    (void)in_sizes; (void)n_in; (void)out_size; (void)d_ws; (void)ws_size;

    for (int t = 0; t <= TSTEPS; ++t) {
        hipLaunchKernelGGL(step_kernel, dim3(NWG), dim3(NTHR), 0, stream,
                           t, X, Wih, Whh, bih, bhh, out);
    }
}